// Round 2
// baseline (148.913 us; speedup 1.0000x reference)
//
#include <hip/hip_runtime.h>

constexpr int CODE_LEN = 1024;
constexpr int INFO_LEN = 512;
constexpr int BATCH    = 2048;
constexpr int ITERS    = 5;
#define CLIPV 15.0f

// f(a,b) = sign(a)*sign(b)*min(|a|,|b|): xor + min(abs,abs) + and_or = 3 VALU
__device__ __forceinline__ float fop(float a, float b) {
    float m = fminf(fabsf(a), fabsf(b));
    unsigned s = (__float_as_uint(a) ^ __float_as_uint(b)) & 0x80000000u;
    return __uint_as_float(__float_as_uint(m) | s);
}
// clip = single v_med3_f32
__device__ __forceinline__ float clipf(float x) {
    return __builtin_amdgcn_fmed3f(x, -CLIPV, CLIPV);
}

// One wave per codeword. Lane owns 16 contiguous words [16*lane .. 16*lane+15].
// stg[s] holds (before right pass) left[s+1]; right pass rewrites stg[s] :=
// right[s+1]; left pass rewrites stg[s-1] := left[s]. stg[9] = rx, never
// overwritten. No __syncthreads in the hot loop; cross-lane via __shfl_xor.
__global__ __launch_bounds__(256, 2) void polar_bp_reg(const float* __restrict__ rx,
                                                       const int* __restrict__ info,
                                                       float* __restrict__ out) {
    __shared__ int RK[CODE_LEN];          // init-only: word -> output rank or -1
    const int t = threadIdx.x;
#pragma unroll
    for (int k = 0; k < 4; ++k) RK[t + 256 * k] = -1;
    __syncthreads();
#pragma unroll
    for (int k = 0; k < 2; ++k) { int kk = t + 256 * k; RK[info[kk]] = kk; }
    __syncthreads();

    const int lane = t & 63;
    const int b    = blockIdx.x * 4 + (t >> 6);

    int   rk[16];
    float fr[16];
#pragma unroll
    for (int j = 0; j < 16; ++j) {
        rk[j] = RK[16 * lane + j];
        fr[j] = (rk[j] < 0) ? CLIPV : 0.f;   // right[0] frozen vector
    }

    float stg[10][16];
    const float4* rxv = (const float4*)(rx + (size_t)b * CODE_LEN + 16 * lane);
#pragma unroll
    for (int q = 0; q < 4; ++q) {
        float4 v = rxv[q];
        stg[9][4 * q + 0] = v.x; stg[9][4 * q + 1] = v.y;
        stg[9][4 * q + 2] = v.z; stg[9][4 * q + 3] = v.w;
    }
#pragma unroll
    for (int s = 0; s < 9; ++s)
#pragma unroll
        for (int j = 0; j < 16; ++j) stg[s][j] = 0.f;

#pragma unroll 1
    for (int it = 0; it < ITERS; ++it) {
        // ========================= RIGHT pass =========================
        // s = 0: r = frozen, l = stg[0] -> stg[0]
#pragma unroll
        for (int j = 0; j < 16; j += 2) {
            float r0 = fr[j], r1 = fr[j + 1];
            float l0 = stg[0][j], l1 = stg[0][j + 1];
            stg[0][j]     = clipf(fop(r0, l1 + r1));
            stg[0][j + 1] = clipf(fop(r0, l0) + r1);
        }
        // s = 1..3: partner within the lane's 16 words
#pragma unroll
        for (int s = 1; s <= 3; ++s) {
            const int st = 1 << s;
#pragma unroll
            for (int j = 0; j < 16; ++j) {
                if ((j & st) == 0) {
                    const int p = j + st;
                    float ru = stg[s - 1][j], rl = stg[s - 1][p];
                    float lu = stg[s][j],     ll = stg[s][p];
                    float nu = clipf(fop(ru, ll + rl));
                    float nl = clipf(fop(ru, lu) + rl);
                    stg[s][j] = nu; stg[s][p] = nl;
                }
            }
        }
        // s = 4..8: cross-lane; exchange exactly the value the partner needs
#pragma unroll
        for (int s = 4; s <= 8; ++s) {
            const int  lm  = 1 << (s - 4);
            const bool upb = (lane & lm) == 0;
            float recv[16];
#pragma unroll
            for (int j = 0; j < 16; ++j) {
                float snd = upb ? fop(stg[s - 1][j], stg[s][j])
                                : (stg[s][j] + stg[s - 1][j]);
                recv[j] = __shfl_xor(snd, lm, 64);
            }
#pragma unroll
            for (int j = 0; j < 16; ++j) {
                float rj = stg[s - 1][j];
                stg[s][j] = upb ? clipf(fop(rj, recv[j]))
                                : clipf(recv[j] + rj);
            }
        }
        // ========================= LEFT pass ==========================
        // s = 9..4: cross-lane (stg[9] = rx is read-only here)
#pragma unroll
        for (int s = 9; s >= 4; --s) {
            const int  lm  = 1 << (s - 4);
            const bool upb = (lane & lm) == 0;
            float recv[16];
#pragma unroll
            for (int j = 0; j < 16; ++j) {
                float snd = upb ? fop(stg[s - 1][j], stg[s][j])
                                : (stg[s][j] + stg[s - 1][j]);
                recv[j] = __shfl_xor(snd, lm, 64);
            }
#pragma unroll
            for (int j = 0; j < 16; ++j) {
                float lj = stg[s][j];
                stg[s - 1][j] = upb ? clipf(fop(lj, recv[j]))
                                    : clipf(recv[j] + lj);
            }
        }
        // s = 3..1: in-lane
#pragma unroll
        for (int s = 3; s >= 1; --s) {
            const int st = 1 << s;
#pragma unroll
            for (int j = 0; j < 16; ++j) {
                if ((j & st) == 0) {
                    const int p = j + st;
                    float lu = stg[s][j],     ll = stg[s][p];
                    float ru = stg[s - 1][j], rl = stg[s - 1][p];
                    float nu = clipf(fop(lu, ll + rl));
                    float nl = clipf(fop(ru, lu) + ll);
                    stg[s - 1][j] = nu; stg[s - 1][p] = nl;
                }
            }
        }
        // s = 0: compute left[0] and emit at info positions (right[0]=0 there)
        float* ob  = out + ((size_t)it * BATCH + b) * INFO_LEN;
        float* ob2 = out + ((size_t)ITERS * BATCH + b) * INFO_LEN;
        const bool last = (it == ITERS - 1);
#pragma unroll
        for (int j = 0; j < 16; j += 2) {
            float l0 = stg[0][j], l1 = stg[0][j + 1];
            float v0 = clipf(fop(l0, l1 + fr[j + 1]));
            float v1 = clipf(fop(fr[j], l0) + l1);
            if (rk[j] >= 0)     { ob[rk[j]] = v0;     if (last) ob2[rk[j]] = v0; }
            if (rk[j + 1] >= 0) { ob[rk[j + 1]] = v1; if (last) ob2[rk[j + 1]] = v1; }
        }
    }
}

extern "C" void kernel_launch(void* const* d_in, const int* in_sizes, int n_in,
                              void* d_out, int out_size, void* d_ws, size_t ws_size,
                              hipStream_t stream) {
    const float* rx   = (const float*)d_in[0];
    const int*   info = (const int*)d_in[1];
    float*       outp = (float*)d_out;
    polar_bp_reg<<<dim3(BATCH / 4), dim3(256), 0, stream>>>(rx, info, outp);
}

// Round 3
// 120.812 us; speedup vs baseline: 1.2326x; 1.2326x over previous
//
#include <hip/hip_runtime.h>

constexpr int CODE_LEN = 1024;
constexpr int INFO_LEN = 512;
constexpr int BATCH    = 2048;
constexpr int ITERS    = 5;
#define CLIPV 15.0f

// f(a,b): v_min with |a|,|b| modifiers + v_xor + v_and_or = 3 VALU
__device__ __forceinline__ float fop(float a, float b) {
    float m = fminf(fabsf(a), fabsf(b));
    unsigned s = (__float_as_uint(a) ^ __float_as_uint(b)) & 0x80000000u;
    return __uint_as_float(__float_as_uint(m) | s);
}
// clip = single v_med3_f32
__device__ __forceinline__ float clipf(float x) {
    return __builtin_amdgcn_fmed3f(x, -CLIPV, CLIPV);
}

// 2 waves per codeword, 8 words per lane (word = w*512 + lane*8 + j).
// stg[s] := left[s+1] before the right pass, right[s+1] after; left pass
// rewrites stg[s-1] := left[s]. stg[9] = rx (read-only). Stages 0-2 in-lane,
// 3-8 shuffle (masks 1..32), 9 via one LDS exchange (1 barrier/iter,
// double-buffered).
__global__ __launch_bounds__(256, 4) void polar_bp2(const float* __restrict__ rx,
                                                    const int* __restrict__ info,
                                                    float* __restrict__ out) {
    __shared__ int   RK[CODE_LEN];   // init-only: position -> output rank / -1
    __shared__ float X[2][8][256];   // cross-wave exchange, double-buffered
    const int t = threadIdx.x;
#pragma unroll
    for (int k = 0; k < 4; ++k) RK[t + 256 * k] = -1;
    __syncthreads();
#pragma unroll
    for (int k = 0; k < 2; ++k) { int kk = t + 256 * k; RK[info[kk]] = kk; }
    __syncthreads();

    const int lane = t & 63;
    const int w    = (t >> 6) & 1;            // wave within codeword pair
    const int b    = blockIdx.x * 2 + (t >> 7);
    const int base = w * 512 + lane * 8;      // codeword-local word base

    int   rk[8];
    float fr[8];
#pragma unroll
    for (int j = 0; j < 8; ++j) {
        rk[j] = RK[base + j];
        fr[j] = (rk[j] < 0) ? CLIPV : 0.f;    // right[0] frozen vector
    }

    float stg[10][8];
    const float4* rxv = (const float4*)(rx + (size_t)b * CODE_LEN + base);
#pragma unroll
    for (int q = 0; q < 2; ++q) {
        float4 v = rxv[q];
        stg[9][4 * q + 0] = v.x; stg[9][4 * q + 1] = v.y;
        stg[9][4 * q + 2] = v.z; stg[9][4 * q + 3] = v.w;
    }
#pragma unroll
    for (int s = 0; s < 9; ++s)
#pragma unroll
        for (int j = 0; j < 8; ++j) stg[s][j] = 0.f;

#pragma unroll 1
    for (int it = 0; it < ITERS; ++it) {
        // ---------------- RIGHT pass ----------------
        // s = 0: r = frozen
#pragma unroll
        for (int j = 0; j < 8; j += 2) {
            float l0 = stg[0][j], l1 = stg[0][j + 1];
            float nu = clipf(fop(fr[j], l1 + fr[j + 1]));
            float nl = clipf(fop(fr[j], l0) + fr[j + 1]);
            stg[0][j] = nu; stg[0][j + 1] = nl;
        }
        // s = 1,2: in-lane butterflies
#pragma unroll
        for (int s = 1; s <= 2; ++s) {
            const int st = 1 << s;
#pragma unroll
            for (int j = 0; j < 8; ++j) if (!(j & st)) {
                const int p = j + st;
                float ru = stg[s - 1][j], rl = stg[s - 1][p];
                float lu = stg[s][j],     ll = stg[s][p];
                stg[s][j] = clipf(fop(ru, ll + rl));
                stg[s][p] = clipf(fop(ru, lu) + rl);
            }
        }
        // s = 3..8: cross-lane shuffles
#pragma unroll
        for (int s = 3; s <= 8; ++s) {
            const int  lm = 1 << (s - 3);
            const bool up = (lane & lm) == 0;
#pragma unroll
            for (int j = 0; j < 8; ++j) {
                float r = stg[s - 1][j], l = stg[s][j];
                float snd = up ? fop(r, l) : (l + r);
                float rc  = __shfl_xor(snd, lm, 64);
                stg[s][j] = clipf(up ? fop(r, rc) : (rc + r));
            }
        }
        // ---------------- LEFT pass -----------------
        // s = 9: cross-wave exchange via LDS (stg[9]=rx read-only, r=stg[8])
        {
            float (*buf)[256] = X[it & 1];
#pragma unroll
            for (int j = 0; j < 8; ++j) {
                float r = stg[8][j], l = stg[9][j];
                buf[j][t] = (w == 0) ? fop(r, l) : (l + r);
            }
            __syncthreads();
#pragma unroll
            for (int j = 0; j < 8; ++j) {
                float rc = buf[j][t ^ 64];
                float l  = stg[9][j];
                stg[8][j] = clipf((w == 0) ? fop(l, rc) : (rc + l));
            }
        }
        // s = 8..3: cross-lane shuffles
#pragma unroll
        for (int s = 8; s >= 3; --s) {
            const int  lm = 1 << (s - 3);
            const bool up = (lane & lm) == 0;
#pragma unroll
            for (int j = 0; j < 8; ++j) {
                float r = stg[s - 1][j], l = stg[s][j];
                float snd = up ? fop(r, l) : (l + r);
                float rc  = __shfl_xor(snd, lm, 64);
                stg[s - 1][j] = clipf(up ? fop(l, rc) : (rc + l));
            }
        }
        // s = 2,1: in-lane butterflies
#pragma unroll
        for (int s = 2; s >= 1; --s) {
            const int st = 1 << s;
#pragma unroll
            for (int j = 0; j < 8; ++j) if (!(j & st)) {
                const int p = j + st;
                float lu = stg[s][j],     ll = stg[s][p];
                float ru = stg[s - 1][j], rl = stg[s - 1][p];
                stg[s - 1][j] = clipf(fop(lu, ll + rl));
                stg[s - 1][p] = clipf(fop(ru, lu) + ll);
            }
        }
        // s = 0: emit left[0] at info positions (right[0]=0 there)
        float* ob  = out + ((size_t)it * BATCH + b) * INFO_LEN;
        float* ob2 = out + ((size_t)ITERS * BATCH + b) * INFO_LEN;
        const bool last = (it == ITERS - 1);
#pragma unroll
        for (int j = 0; j < 8; j += 2) {
            float l0 = stg[0][j], l1 = stg[0][j + 1];
            float v0 = clipf(fop(l0, l1 + fr[j + 1]));
            float v1 = clipf(fop(fr[j], l0) + l1);
            if (rk[j]     >= 0) { ob[rk[j]] = v0;     if (last) ob2[rk[j]] = v0; }
            if (rk[j + 1] >= 0) { ob[rk[j + 1]] = v1; if (last) ob2[rk[j + 1]] = v1; }
        }
    }
}

extern "C" void kernel_launch(void* const* d_in, const int* in_sizes, int n_in,
                              void* d_out, int out_size, void* d_ws, size_t ws_size,
                              hipStream_t stream) {
    const float* rx   = (const float*)d_in[0];
    const int*   info = (const int*)d_in[1];
    float*       outp = (float*)d_out;
    polar_bp2<<<dim3(BATCH / 2), dim3(256), 0, stream>>>(rx, info, outp);
}